// Round 1
// baseline (243.354 us; speedup 1.0000x reference)
//
#include <hip/hip_runtime.h>

#define W 1024
#define H 1024
#define NB 16
#define TX 32
#define TY 32
#define RX 38  // TX + 6 halo
#define RY 38  // TY + 6 halo

// Fused separable-conv SSIM kernel.
// Each block computes a 32x32 output tile for one image index.
// LDS: raw tiles (3 x 38x38) + 8-channel horizontal-conv buffer (8 x 38x32).
__global__ __launch_bounds__(256) void ssim_main(
    const float* __restrict__ img1, const float* __restrict__ img2,
    const float* __restrict__ img3, const float* __restrict__ win,
    float* __restrict__ partial)
{
    __shared__ float raw1[RY][RX];
    __shared__ float raw2[RY][RX];
    __shared__ float raw3[RY][RX];
    __shared__ float hbuf[8][RY][TX];
    __shared__ float wavesum[4];

    const int tid = threadIdx.x;
    const int b  = blockIdx.z;
    const int x0 = blockIdx.x * TX;
    const int y0 = blockIdx.y * TY;
    const size_t imoff = (size_t)b * (size_t)(W * H);
    const float* p1 = img1 + imoff;
    const float* p2 = img2 + imoff;
    const float* p3 = img3 + imoff;

    // Derive the separable 1-D gaussian from the 2-D window:
    // win[3][3] = g3^2, win[3][j] = g3*gj  ->  gj = win[21+j]/sqrt(win[24])
    float g[7];
    {
        const float g3 = sqrtf(win[24]);
        #pragma unroll
        for (int j = 0; j < 7; ++j) g[j] = win[21 + j] / g3;
    }

    // ---- Stage A: global -> LDS raw tiles (zero padding outside image) ----
    for (int i = tid; i < RY * RX; i += 256) {
        const int r = i / RX;
        const int c = i - r * RX;
        const int gy = y0 + r - 3;
        const int gx = x0 + c - 3;
        const bool ok = (gy >= 0) & (gy < H) & (gx >= 0) & (gx < W);
        const size_t off = (size_t)gy * W + gx;
        raw1[r][c] = ok ? p1[off] : 0.0f;
        raw2[r][c] = ok ? p2[off] : 0.0f;
        raw3[r][c] = ok ? p3[off] : 0.0f;
    }
    __syncthreads();

    // ---- Stage B: horizontal conv of the 8 product channels ----
    for (int i = tid; i < RY * TX; i += 256) {
        const int r = i >> 5;       // 0..37
        const int c = i & 31;       // 0..31
        float a0 = 0.f, a1 = 0.f, a2 = 0.f, a3 = 0.f;
        float a4 = 0.f, a5 = 0.f, a6 = 0.f, a7 = 0.f;
        #pragma unroll
        for (int dx = 0; dx < 7; ++dx) {
            const float wgt = g[dx];
            const float v1 = raw1[r][c + dx];
            const float v2 = raw2[r][c + dx];
            const float v3 = raw3[r][c + dx];
            a0 += wgt * v1;
            a1 += wgt * v2;
            a2 += wgt * v3;
            a3 += wgt * v1 * v1;
            a4 += wgt * v2 * v2;
            a5 += wgt * v3 * v3;
            a6 += wgt * v1 * v2;
            a7 += wgt * v1 * v3;
        }
        hbuf[0][r][c] = a0; hbuf[1][r][c] = a1;
        hbuf[2][r][c] = a2; hbuf[3][r][c] = a3;
        hbuf[4][r][c] = a4; hbuf[5][r][c] = a5;
        hbuf[6][r][c] = a6; hbuf[7][r][c] = a7;
    }
    __syncthreads();

    // ---- Stage C: vertical conv + SSIM math + local accumulate ----
    float lsum = 0.0f;
    for (int i = tid; i < TY * TX; i += 256) {
        const int ty = i >> 5;
        const int tx = i & 31;
        float s0 = 0.f, s1 = 0.f, s2 = 0.f, s3 = 0.f;
        float s4 = 0.f, s5 = 0.f, s6 = 0.f, s7 = 0.f;
        #pragma unroll
        for (int dy = 0; dy < 7; ++dy) {
            const float wgt = g[dy];
            s0 += wgt * hbuf[0][ty + dy][tx];
            s1 += wgt * hbuf[1][ty + dy][tx];
            s2 += wgt * hbuf[2][ty + dy][tx];
            s3 += wgt * hbuf[3][ty + dy][tx];
            s4 += wgt * hbuf[4][ty + dy][tx];
            s5 += wgt * hbuf[5][ty + dy][tx];
            s6 += wgt * hbuf[6][ty + dy][tx];
            s7 += wgt * hbuf[7][ty + dy][tx];
        }
        const float mu1 = s0, mu2 = s1, mu3 = s2;
        const float sig1 = s3 - mu1 * mu1;
        const float sig2 = s4 - mu2 * mu2;
        const float sig3 = s5 - mu3 * mu3;
        const float sig12 = s6 - mu1 * mu2;
        const float sig13 = s7 - mu1 * mu3;
        const float C2 = 9.0e-4f;  // 0.03^2
        const float m12 = (2.0f * sig12 + C2) / (sig1 + sig2 + C2);
        const float m13 = (2.0f * sig13 + C2) / (sig1 + sig3 + C2);
        lsum += (mu2 > mu3) ? m12 : m13;
    }

    // ---- Block reduction (deterministic: shuffle tree + LDS) ----
    #pragma unroll
    for (int o = 32; o > 0; o >>= 1) lsum += __shfl_down(lsum, o, 64);
    if ((tid & 63) == 0) wavesum[tid >> 6] = lsum;
    __syncthreads();
    if (tid == 0) {
        const float t = (wavesum[0] + wavesum[1]) + (wavesum[2] + wavesum[3]);
        partial[((size_t)blockIdx.z * gridDim.y + blockIdx.y) * gridDim.x + blockIdx.x] = t;
    }
}

// Deterministic final reduction: one block, fixed summation order, f64 accum.
__global__ __launch_bounds__(256) void ssim_reduce(
    const float* __restrict__ partial, float* __restrict__ out, int n)
{
    __shared__ double sh[256];
    const int tid = threadIdx.x;
    double s = 0.0;
    for (int i = tid; i < n; i += 256) s += (double)partial[i];
    sh[tid] = s;
    __syncthreads();
    for (int o = 128; o > 0; o >>= 1) {
        if (tid < o) sh[tid] += sh[tid + o];
        __syncthreads();
    }
    if (tid == 0) out[0] = (float)(sh[0] / (double)((size_t)NB * W * H));
}

extern "C" void kernel_launch(void* const* d_in, const int* in_sizes, int n_in,
                              void* d_out, int out_size, void* d_ws, size_t ws_size,
                              hipStream_t stream) {
    const float* img1 = (const float*)d_in[0];
    const float* img2 = (const float*)d_in[1];
    const float* img3 = (const float*)d_in[2];
    const float* win  = (const float*)d_in[3];
    float* out = (float*)d_out;
    float* partial = (float*)d_ws;

    dim3 grid(W / TX, H / TY, NB);
    ssim_main<<<grid, 256, 0, stream>>>(img1, img2, img3, win, partial);

    const int nblk = (W / TX) * (H / TY) * NB;
    ssim_reduce<<<1, 256, 0, stream>>>(partial, out, nblk);
}

// Round 2
// 241.792 us; speedup vs baseline: 1.0065x; 1.0065x over previous
//
#include <hip/hip_runtime.h>

#define W 1024
#define H 1024
#define NB 16
#define TX 32
#define TY 32
#define RXP 40  // padded raw row stride (38 data cols + 2 pad) -> 160B rows, float4-aligned
#define RY 38   // TY + 6 halo

// Fused separable-conv SSIM kernel, register-tiled to minimize LDS instruction count.
__global__ __launch_bounds__(256) void ssim_main(
    const float* __restrict__ img1, const float* __restrict__ img2,
    const float* __restrict__ img3, const float* __restrict__ win,
    float* __restrict__ partial)
{
    __shared__ __align__(16) float raw1[RY][RXP];
    __shared__ __align__(16) float raw2[RY][RXP];
    __shared__ __align__(16) float raw3[RY][RXP];
    __shared__ __align__(16) float hbuf[8][RY][TX];
    __shared__ float wavesum[4];

    const int tid = threadIdx.x;
    const int b  = blockIdx.z;
    const int x0 = blockIdx.x * TX;
    const int y0 = blockIdx.y * TY;
    const size_t imoff = (size_t)b * (size_t)(W * H);
    const float* p1 = img1 + imoff;
    const float* p2 = img2 + imoff;
    const float* p3 = img3 + imoff;

    // Separable 1-D gaussian from the 2-D window: g[j] = win[3][j] / sqrt(win[3][3])
    float g[7];
    {
        const float g3 = sqrtf(win[24]);
        #pragma unroll
        for (int j = 0; j < 7; ++j) g[j] = win[21 + j] / g3;
    }

    // ---- Stage A: global -> LDS raw tiles (zero padding outside image) ----
    for (int i = tid; i < RY * RXP; i += 256) {
        const int r = i / RXP;
        const int c = i - r * RXP;
        const int gy = y0 + r - 3;
        const int gx = x0 + c - 3;
        const bool ok = (gy >= 0) & (gy < H) & (gx >= 0) & (gx < W) & (c < 38);
        const size_t off = (size_t)gy * W + gx;
        raw1[r][c] = ok ? p1[off] : 0.0f;
        raw2[r][c] = ok ? p2[off] : 0.0f;
        raw3[r][c] = ok ? p3[off] : 0.0f;
    }
    __syncthreads();

    // ---- Stage B: horizontal conv, 4 consecutive x per thread, b128 LDS loads ----
    // tasks: 38 rows x 8 col-groups = 304
    for (int i = tid; i < RY * 8; i += 256) {
        const int r  = i >> 3;
        const int c0 = (i & 7) << 2;
        float V1[12], V2[12], V3[12];
        *(float4*)&V1[0] = *(const float4*)&raw1[r][c0];
        *(float4*)&V1[4] = *(const float4*)&raw1[r][c0 + 4];
        *(float4*)&V1[8] = *(const float4*)&raw1[r][c0 + 8];
        *(float4*)&V2[0] = *(const float4*)&raw2[r][c0];
        *(float4*)&V2[4] = *(const float4*)&raw2[r][c0 + 4];
        *(float4*)&V2[8] = *(const float4*)&raw2[r][c0 + 8];
        *(float4*)&V3[0] = *(const float4*)&raw3[r][c0];
        *(float4*)&V3[4] = *(const float4*)&raw3[r][c0 + 4];
        *(float4*)&V3[8] = *(const float4*)&raw3[r][c0 + 8];

        float acc[8][4];
        #pragma unroll
        for (int j = 0; j < 4; ++j) {
            float a0 = 0.f, a1 = 0.f, a2 = 0.f, a3 = 0.f;
            float a4 = 0.f, a5 = 0.f, a6 = 0.f, a7 = 0.f;
            #pragma unroll
            for (int dx = 0; dx < 7; ++dx) {
                const float w  = g[dx];
                const float v1 = V1[j + dx];
                const float v2 = V2[j + dx];
                const float v3 = V3[j + dx];
                const float w1 = w * v1;
                const float w2 = w * v2;
                const float w3 = w * v3;
                a0 += w1;
                a1 += w2;
                a2 += w3;
                a3 += w1 * v1;
                a4 += w2 * v2;
                a5 += w3 * v3;
                a6 += w1 * v2;
                a7 += w1 * v3;
            }
            acc[0][j] = a0; acc[1][j] = a1; acc[2][j] = a2; acc[3][j] = a3;
            acc[4][j] = a4; acc[5][j] = a5; acc[6][j] = a6; acc[7][j] = a7;
        }
        #pragma unroll
        for (int ch = 0; ch < 8; ++ch) {
            *(float4*)&hbuf[ch][r][c0] =
                make_float4(acc[ch][0], acc[ch][1], acc[ch][2], acc[ch][3]);
        }
    }
    __syncthreads();

    // ---- Stage C: vertical conv, 4-tall output column per thread ----
    const int tx = tid & 31;
    const int r0 = (tid >> 5) << 2;  // 0,4,...,28

    float s[8][4];
    #pragma unroll
    for (int ch = 0; ch < 8; ++ch) {
        const float* base = &hbuf[ch][r0][tx];
        float v[10];
        #pragma unroll
        for (int dy = 0; dy < 10; ++dy) v[dy] = base[dy * TX];
        #pragma unroll
        for (int j = 0; j < 4; ++j) {
            float t = 0.f;
            #pragma unroll
            for (int dy = 0; dy < 7; ++dy) t += g[dy] * v[j + dy];
            s[ch][j] = t;
        }
    }

    float lsum = 0.0f;
    #pragma unroll
    for (int j = 0; j < 4; ++j) {
        const float mu1 = s[0][j], mu2 = s[1][j], mu3 = s[2][j];
        const float sig1  = s[3][j] - mu1 * mu1;
        const float sig2  = s[4][j] - mu2 * mu2;
        const float sig3  = s[5][j] - mu3 * mu3;
        const float sig12 = s[6][j] - mu1 * mu2;
        const float sig13 = s[7][j] - mu1 * mu3;
        const float C2 = 9.0e-4f;  // 0.03^2
        const float m12 = (2.0f * sig12 + C2) / (sig1 + sig2 + C2);
        const float m13 = (2.0f * sig13 + C2) / (sig1 + sig3 + C2);
        lsum += (mu2 > mu3) ? m12 : m13;
    }

    // ---- Block reduction (deterministic) ----
    #pragma unroll
    for (int o = 32; o > 0; o >>= 1) lsum += __shfl_down(lsum, o, 64);
    if ((tid & 63) == 0) wavesum[tid >> 6] = lsum;
    __syncthreads();
    if (tid == 0) {
        const float t = (wavesum[0] + wavesum[1]) + (wavesum[2] + wavesum[3]);
        partial[((size_t)blockIdx.z * gridDim.y + blockIdx.y) * gridDim.x + blockIdx.x] = t;
    }
}

// Deterministic final reduction: one block, fixed summation order, f64 accum.
__global__ __launch_bounds__(256) void ssim_reduce(
    const float* __restrict__ partial, float* __restrict__ out, int n)
{
    __shared__ double sh[256];
    const int tid = threadIdx.x;
    double s = 0.0;
    for (int i = tid; i < n; i += 256) s += (double)partial[i];
    sh[tid] = s;
    __syncthreads();
    for (int o = 128; o > 0; o >>= 1) {
        if (tid < o) sh[tid] += sh[tid + o];
        __syncthreads();
    }
    if (tid == 0) out[0] = (float)(sh[0] / (double)((size_t)NB * W * H));
}

extern "C" void kernel_launch(void* const* d_in, const int* in_sizes, int n_in,
                              void* d_out, int out_size, void* d_ws, size_t ws_size,
                              hipStream_t stream) {
    const float* img1 = (const float*)d_in[0];
    const float* img2 = (const float*)d_in[1];
    const float* img3 = (const float*)d_in[2];
    const float* win  = (const float*)d_in[3];
    float* out = (float*)d_out;
    float* partial = (float*)d_ws;

    dim3 grid(W / TX, H / TY, NB);
    ssim_main<<<grid, 256, 0, stream>>>(img1, img2, img3, win, partial);

    const int nblk = (W / TX) * (H / TY) * NB;
    ssim_reduce<<<1, 256, 0, stream>>>(partial, out, nblk);
}